// Round 4
// baseline (599.584 us; speedup 1.0000x reference)
//
#include <hip/hip_runtime.h>
#include <hip/hip_bf16.h>
#include <stdint.h>
#include <cmath>

typedef __bf16 bf16x8 __attribute__((ext_vector_type(8)));
typedef float f32x4 __attribute__((ext_vector_type(4)));

#define NB 8
#define NS 2048
#define ND 1024
#define NO 512

__device__ __forceinline__ unsigned short f2bf(float f) {
  union { float f; uint32_t u; } c;
  c.f = f;
  uint32_t u = c.u;
  uint32_t r = (u + 0x7fffu + ((u >> 16) & 1u)) >> 16;
  return (unsigned short)r;
}

__device__ __forceinline__ void glds16(const void* g, void* l) {
  __builtin_amdgcn_global_load_lds(
      (const __attribute__((address_space(1))) unsigned int*)g,
      (__attribute__((address_space(3))) unsigned int*)l, 16, 0, 0);
}

// ---------------- cast x (fp32 -> bf16), 8 elems/thread ----------------
__global__ void cast_x_kernel(const float* __restrict__ in,
                              unsigned short* __restrict__ out, int n8) {
  int i = blockIdx.x * blockDim.x + threadIdx.x;
  if (i >= n8) return;
  const float4* p = reinterpret_cast<const float4*>(in) + 2 * (size_t)i;
  float4 a = p[0], b = p[1];
  union { unsigned short us[8]; int4 v; } r;
  r.us[0] = f2bf(a.x); r.us[1] = f2bf(a.y); r.us[2] = f2bf(a.z); r.us[3] = f2bf(a.w);
  r.us[4] = f2bf(b.x); r.us[5] = f2bf(b.y); r.us[6] = f2bf(b.z); r.us[7] = f2bf(b.w);
  reinterpret_cast<int4*>(out)[i] = r.v;
}

// ------------- transpose+cast weights: in[R][C] f32 -> out[C][R] bf16 -------------
__global__ void transpose_cast_kernel(const float* __restrict__ in,
                                      unsigned short* __restrict__ out,
                                      int R, int C) {
  __shared__ unsigned short t[32][33];
  int bx = blockIdx.x;  // C/32
  int by = blockIdx.y;  // R/32
  int x = threadIdx.x & 31, y = threadIdx.x >> 5;  // y: 0..7
#pragma unroll
  for (int j = 0; j < 4; j++) {
    int r = by * 32 + y + j * 8;
    int c = bx * 32 + x;
    t[y + j * 8][x] = f2bf(in[(size_t)r * C + c]);
  }
  __syncthreads();
#pragma unroll
  for (int j = 0; j < 4; j++) {
    int c = bx * 32 + y + j * 8;
    int r = by * 32 + x;
    out[(size_t)c * R + r] = t[x][y + j * 8];
  }
}

// ------------- transpose V: [B][S][O] bf16 -> [B][O][S] bf16 -------------
__global__ void transpose_v_kernel(const unsigned short* __restrict__ in,
                                   unsigned short* __restrict__ out) {
  __shared__ unsigned short t[32][33];
  int b = blockIdx.z;
  int bo = blockIdx.x;  // O/32
  int bs = blockIdx.y;  // S/32
  const unsigned short* ib = in + (size_t)b * NS * NO;
  unsigned short* ob = out + (size_t)b * NO * NS;
  int x = threadIdx.x & 31, y = threadIdx.x >> 5;
#pragma unroll
  for (int j = 0; j < 4; j++)
    t[y + j * 8][x] = ib[(size_t)(bs * 32 + y + j * 8) * NO + bo * 32 + x];
  __syncthreads();
#pragma unroll
  for (int j = 0; j < 4; j++)
    ob[(size_t)(bo * 32 + y + j * 8) * NS + bs * 32 + x] = t[x][y + j * 8];
}

// ------------- GEMM: C[M][N] = A[M][K] @ Bt[N][K]^T + bias, bf16 in/out -------------
__global__ __launch_bounds__(256, 2) void gemm_bias_kernel(
    const unsigned short* __restrict__ A, const unsigned short* __restrict__ Bt,
    const float* __restrict__ bias, unsigned short* __restrict__ C,
    int M, int N, int K) {
  __shared__ unsigned short lA[128 * 32];
  __shared__ unsigned short lB[128 * 32];
  const int tid = threadIdx.x;
  const int w = tid >> 6, l = tid & 63;
  const int m0 = blockIdx.x * 128, n0 = blockIdx.y * 128;
  const int wr = w >> 1, wc = w & 1;
  const int lr16 = l & 15, lg = l >> 4;
  f32x4 acc[4][4];
#pragma unroll
  for (int i = 0; i < 4; i++)
#pragma unroll
    for (int j = 0; j < 4; j++) acc[i][j] = (f32x4){0.f, 0.f, 0.f, 0.f};
  const int srow = w * 32 + (l >> 2);
  const int sk = (l & 3) * 8;
  for (int k0 = 0; k0 < K; k0 += 32) {
#pragma unroll
    for (int j = 0; j < 2; j++) {
      glds16(&A[(size_t)(m0 + srow + j * 16) * K + k0 + sk], &lA[w * 1024 + j * 512]);
      glds16(&Bt[(size_t)(n0 + srow + j * 16) * K + k0 + sk], &lB[w * 1024 + j * 512]);
    }
    __syncthreads();
    bf16x8 af[4], bfr[4];
#pragma unroll
    for (int mi = 0; mi < 4; mi++)
      af[mi] = *reinterpret_cast<const bf16x8*>(&lA[(wr * 64 + mi * 16 + lr16) * 32 + lg * 8]);
#pragma unroll
    for (int ni = 0; ni < 4; ni++)
      bfr[ni] = *reinterpret_cast<const bf16x8*>(&lB[(wc * 64 + ni * 16 + lr16) * 32 + lg * 8]);
#pragma unroll
    for (int mi = 0; mi < 4; mi++)
#pragma unroll
      for (int ni = 0; ni < 4; ni++)
        acc[mi][ni] = __builtin_amdgcn_mfma_f32_16x16x32_bf16(af[mi], bfr[ni], acc[mi][ni], 0, 0, 0);
    __syncthreads();
  }
#pragma unroll
  for (int ni = 0; ni < 4; ni++) {
    int col = n0 + wc * 64 + ni * 16 + lr16;
    float bv = bias[col];
#pragma unroll
    for (int mi = 0; mi < 4; mi++) {
#pragma unroll
      for (int i = 0; i < 4; i++) {
        int row = m0 + wr * 64 + mi * 16 + lg * 4 + i;
        C[(size_t)row * N + col] = f2bf(acc[mi][ni][i] + bv);
      }
    }
  }
}

// ------------- Flash attention SPLIT-KV: each block does k-tiles [lo,hi) of one (b,qi) -------------
// Writes unnormalized partial O (bf16) + (m,l) f32 to workspace; combine_kernel merges.
// Block-id ordering is LPT: first 256 bids = heavy halves (qi desc), last 256 = light (qi asc),
// so each CU's two resident blocks sum to ~16.5 k-tiles. b stays in low 3 bits -> XCD pinning.
__global__ __launch_bounds__(256, 2) void flash_split_kernel(
    const unsigned short* __restrict__ Q, const unsigned short* __restrict__ K,
    const unsigned short* __restrict__ Vt, unsigned short* __restrict__ opart,
    float* __restrict__ ml) {
  __shared__ unsigned short ubuf[3 * 8192];  // 3 x 16KB pipeline buffers
  __shared__ unsigned short lP[64 * 64];     // 8KB, swizzled
  const int bid = blockIdx.x;
  const int b = bid & 7;
  const int t = bid >> 3;
  int qi, half;
  if (t < 32) { qi = 31 - (t >> 1); half = t & 1; }      // heavy halves first
  else        { int u2 = t - 32; qi = u2 >> 1; half = u2 & 1; }  // light halves last
  const int nkt = qi + 1;
  const int h = (qi + 2) >> 1;           // ceil(nkt/2)
  const int lo = half ? h : 0;
  const int hi = half ? nkt : h;
  const int total = 12 * (hi - lo);

  const int tid = threadIdx.x, w = tid >> 6, l = tid & 63;
  const unsigned short* Qb = Q + (size_t)b * NS * ND;
  const unsigned short* Kb = K + (size_t)b * NS * ND;
  const unsigned short* Vb = Vt + (size_t)b * NO * NS;
  const int q0 = qi * 64;
  const int lr16 = l & 15, lg = l >> 4;

  // ---- Q tile into registers: lane holds row (w*16+lr16), d-slice (c*32 + lg*8) ----
  bf16x8 qreg[32];
  {
    const unsigned short* qrow = &Qb[(size_t)(q0 + w * 16 + lr16) * ND + lg * 8];
#pragma unroll
    for (int c = 0; c < 32; c++)
      qreg[c] = *reinterpret_cast<const bf16x8*>(qrow + c * 32);
  }

  f32x4 acc_o[32];
#pragma unroll
  for (int f = 0; f < 32; f++) acc_o[f] = (f32x4){0.f, 0.f, 0.f, 0.f};
  float m_s[4], l_s[4];
#pragma unroll
  for (int i = 0; i < 4; i++) { m_s[i] = -INFINITY; l_s[i] = 0.f; }
  const float sc = 0.03125f * 1.4426950408889634f;  // 1/sqrt(1024) * log2(e)

  // stage relative unit g (k-tile lo + g/12) into buffer g%3
  auto stage = [&](int g) {
    int ki = lo + g / 12, u = g - (g / 12) * 12;
    int k0 = ki * 64;
    unsigned short* dst = &ubuf[(g % 3) * 8192];
    if (u < 8) {  // K unit u: [64 kv][128 d], d-range u*128
#pragma unroll
      for (int j = 0; j < 4; j++) {
        int row = j * 16 + w * 4 + (l >> 4);
        int gl = (l & 15) ^ (row & 7);  // inverse-swizzled source granule
        glds16(&Kb[(size_t)(k0 + row) * ND + u * 128 + gl * 8],
               dst + j * 2048 + w * 512);
      }
    } else {  // V unit nc: [128 O][64 kv], O-range nc*128
      int nc = u - 8;
#pragma unroll
      for (int j = 0; j < 4; j++) {
        int row = j * 32 + w * 8 + (l >> 3);
        int gl = (l & 7) ^ (row & 7);
        glds16(&Vb[(size_t)(nc * 128 + row) * NS + k0 + gl * 8],
               dst + j * 2048 + w * 512);
      }
    }
  };

  if (total > 0) {
    stage(0);
    stage(1);

    bf16x8 pa0 = {}, pa1 = {};
    for (int ki = lo; ki < hi; ++ki) {
      const int gbase = (ki - lo) * 12;
      f32x4 accs[4];
#pragma unroll
      for (int f = 0; f < 4; f++) accs[f] = (f32x4){0.f, 0.f, 0.f, 0.f};

#pragma unroll
      for (int u = 0; u < 12; ++u) {
        const int g = gbase + u;
        const bool isLast = (g == total - 1);
        if (!isLast)
          asm volatile("s_waitcnt vmcnt(4) lgkmcnt(0)\ns_barrier" ::: "memory");
        else
          asm volatile("s_waitcnt vmcnt(0) lgkmcnt(0)\ns_barrier" ::: "memory");
        if (g + 2 < total) stage(g + 2);
        const unsigned short* bp = &ubuf[(g % 3) * 8192];

        if (u < 8) {
          // ---- QK^T unit: S += Q[d-slice] * K[d-slice]^T ----
#pragma unroll
          for (int ks = 0; ks < 4; ks++) {
            bf16x8 a = qreg[u * 4 + ks];
#pragma unroll
            for (int fn = 0; fn < 4; fn++) {
              int row = fn * 16 + lr16;
              int p = (ks * 4 + lg) ^ (row & 7);
              bf16x8 bb = *reinterpret_cast<const bf16x8*>(&bp[row * 128 + p * 8]);
              accs[fn] = __builtin_amdgcn_mfma_f32_16x16x32_bf16(a, bb, accs[fn], 0, 0, 0);
            }
          }
          if (u == 7) {
            // ---- online softmax (wave-parallel, in-register) ----
            const bool diag = (ki == qi);
            float alpha[4];
#pragma unroll
            for (int i = 0; i < 4; i++) {
              float v0 = accs[0][i] * sc, v1 = accs[1][i] * sc;
              float v2 = accs[2][i] * sc, v3 = accs[3][i] * sc;
              if (diag) {
                int qr = w * 16 + lg * 4 + i;
                if (lr16 > qr) v0 = -INFINITY;
                if (16 + lr16 > qr) v1 = -INFINITY;
                if (32 + lr16 > qr) v2 = -INFINITY;
                if (48 + lr16 > qr) v3 = -INFINITY;
              }
              float pm = fmaxf(fmaxf(v0, v1), fmaxf(v2, v3));
              pm = fmaxf(pm, __shfl_xor(pm, 1));
              pm = fmaxf(pm, __shfl_xor(pm, 2));
              pm = fmaxf(pm, __shfl_xor(pm, 4));
              pm = fmaxf(pm, __shfl_xor(pm, 8));
              float mn = fmaxf(m_s[i], pm);
              float al = exp2f(m_s[i] - mn);
              float p0 = exp2f(v0 - mn), p1 = exp2f(v1 - mn);
              float p2 = exp2f(v2 - mn), p3 = exp2f(v3 - mn);
              float rs = (p0 + p1) + (p2 + p3);
              rs += __shfl_xor(rs, 1);
              rs += __shfl_xor(rs, 2);
              rs += __shfl_xor(rs, 4);
              rs += __shfl_xor(rs, 8);
              l_s[i] = l_s[i] * al + rs;
              m_s[i] = mn;
              alpha[i] = al;
              accs[0][i] = p0; accs[1][i] = p1; accs[2][i] = p2; accs[3][i] = p3;
            }
#pragma unroll
            for (int f = 0; f < 32; f++)
#pragma unroll
              for (int i = 0; i < 4; i++) acc_o[f][i] *= alpha[i];
            // ---- P -> LDS (bf16, swizzled) ----
#pragma unroll
            for (int fn = 0; fn < 4; fn++)
#pragma unroll
              for (int i = 0; i < 4; i++) {
                int pr = w * 16 + lg * 4 + i;
                int pg = (fn * 2 + (lr16 >> 3)) ^ (pr & 7);
                lP[pr * 64 + pg * 8 + (lr16 & 7)] = f2bf(accs[fn][i]);
              }
          }
        } else {
          // ---- PV unit nc: O += P * V ----
          const int nc = u - 8;
          if (u == 8) {
            int prow = w * 16 + lr16;
            pa0 = *reinterpret_cast<const bf16x8*>(&lP[prow * 64 + ((0 + lg) ^ (prow & 7)) * 8]);
            pa1 = *reinterpret_cast<const bf16x8*>(&lP[prow * 64 + ((4 + lg) ^ (prow & 7)) * 8]);
          }
#pragma unroll
          for (int fc = 0; fc < 8; fc++) {
            int row = fc * 16 + lr16;
            int p0i = (0 + lg) ^ (row & 7);
            int p1i = (4 + lg) ^ (row & 7);
            bf16x8 b0 = *reinterpret_cast<const bf16x8*>(&bp[row * 64 + p0i * 8]);
            bf16x8 b1 = *reinterpret_cast<const bf16x8*>(&bp[row * 64 + p1i * 8]);
            int f = nc * 8 + fc;
            acc_o[f] = __builtin_amdgcn_mfma_f32_16x16x32_bf16(pa0, b0, acc_o[f], 0, 0, 0);
            acc_o[f] = __builtin_amdgcn_mfma_f32_16x16x32_bf16(pa1, b1, acc_o[f], 0, 0, 0);
          }
        }
      }
    }
  }

  // ---- epilogue: write unnormalized partial O (bf16) + m,l (f32) ----
  const int slot = (qi * 2 + half) * 8 + b;
  unsigned short* op = opart + (size_t)slot * 64 * 512;
#pragma unroll
  for (int nc = 0; nc < 4; nc++)
#pragma unroll
    for (int fc = 0; fc < 8; fc++)
#pragma unroll
      for (int i = 0; i < 4; i++) {
        int row = w * 16 + lg * 4 + i;
        int col = nc * 128 + fc * 16 + lr16;
        op[(size_t)row * 512 + col] = f2bf(acc_o[nc * 8 + fc][i]);
      }
  float* mlp = ml + slot * 128;
  if (lr16 == 0) {
#pragma unroll
    for (int i = 0; i < 4; i++) {
      int row = w * 16 + lg * 4 + i;
      mlp[row] = m_s[i];
      mlp[64 + row] = l_s[i];
    }
  }
}

// ------------- combine: merge two partials -> final fp32 out -------------
__global__ __launch_bounds__(256) void combine_kernel(
    const unsigned short* __restrict__ opart, const float* __restrict__ ml,
    float* __restrict__ Out) {
  const int bid = blockIdx.x;
  const int b = bid & 7, qi = bid >> 3;
  const int tid = threadIdx.x;
  const int c8 = (tid & 63) * 8;
  const int rbase = (tid >> 6) * 16;
  const int sA = (qi * 2 + 0) * 8 + b;
  const int sB = sA + 8;
  const unsigned short* OA = opart + (size_t)sA * 32768;
  const unsigned short* OB = opart + (size_t)sB * 32768;
  const float* mlA = ml + sA * 128;
  const float* mlB = ml + sB * 128;
  float* ob = Out + ((size_t)b * NS + qi * 64) * NO;
#pragma unroll
  for (int rr = 0; rr < 16; rr++) {
    int r = rbase + rr;
    float mA = mlA[r], lA = mlA[64 + r];
    float mB = mlB[r], lB = mlB[64 + r];
    float m = fmaxf(mA, mB);
    float eA = exp2f(mA - m);
    float eB = (mB == -INFINITY) ? 0.f : exp2f(mB - m);
    float inv = 1.0f / (eA * lA + eB * lB);
    bf16x8 a = *reinterpret_cast<const bf16x8*>(&OA[(size_t)r * 512 + c8]);
    bf16x8 bb = *reinterpret_cast<const bf16x8*>(&OB[(size_t)r * 512 + c8]);
    float4 o0, o1;
    o0.x = ((float)a[0] * eA + (float)bb[0] * eB) * inv;
    o0.y = ((float)a[1] * eA + (float)bb[1] * eB) * inv;
    o0.z = ((float)a[2] * eA + (float)bb[2] * eB) * inv;
    o0.w = ((float)a[3] * eA + (float)bb[3] * eB) * inv;
    o1.x = ((float)a[4] * eA + (float)bb[4] * eB) * inv;
    o1.y = ((float)a[5] * eA + (float)bb[5] * eB) * inv;
    o1.z = ((float)a[6] * eA + (float)bb[6] * eB) * inv;
    o1.w = ((float)a[7] * eA + (float)bb[7] * eB) * inv;
    float4* dst = reinterpret_cast<float4*>(&ob[(size_t)r * 512 + c8]);
    dst[0] = o0;
    dst[1] = o1;
  }
}

extern "C" void kernel_launch(void* const* d_in, const int* in_sizes, int n_in,
                              void* d_out, int out_size, void* d_ws, size_t ws_size,
                              hipStream_t stream) {
  const float* x = (const float*)d_in[0];
  const float* Wq = (const float*)d_in[1];
  const float* bq = (const float*)d_in[2];
  const float* Wk = (const float*)d_in[3];
  const float* bk = (const float*)d_in[4];
  const float* Wv = (const float*)d_in[5];
  const float* bv = (const float*)d_in[6];
  float* out = (float*)d_out;
  char* ws = (char*)d_ws;

  // workspace layout (bytes)
  unsigned short* xb  = (unsigned short*)(ws + 0);          // 33,554,432 (dead after GEMMs)
  unsigned short* wqt = (unsigned short*)(ws + 33554432);   //  2,097,152
  unsigned short* wkt = (unsigned short*)(ws + 35651584);   //  2,097,152
  unsigned short* wvt = (unsigned short*)(ws + 37748736);   //  1,048,576
  unsigned short* Qb  = (unsigned short*)(ws + 38797312);   // 33,554,432
  unsigned short* Kb  = (unsigned short*)(ws + 72351744);   // 33,554,432
  unsigned short* Vb  = (unsigned short*)(ws + 105906176);  // 16,777,216 (dead after transpose_v)
  unsigned short* Vtb = (unsigned short*)(ws + 122683392);  // 16,777,216  (end ~133MB)
  // reuse dead regions for split-kv partials:
  unsigned short* opart = xb;                               // 512*64*512*2 = 33,554,432 (fits xb exactly)
  float* mlbuf = (float*)(ws + 105906176);                  // 512*128*4 = 262,144 (in Vb region)

  // 1) casts
  cast_x_kernel<<<8192, 256, 0, stream>>>(x, xb, (NB * NS * ND) / 8);
  transpose_cast_kernel<<<dim3(32, 32), 256, 0, stream>>>(Wq, wqt, ND, ND);
  transpose_cast_kernel<<<dim3(32, 32), 256, 0, stream>>>(Wk, wkt, ND, ND);
  transpose_cast_kernel<<<dim3(16, 32), 256, 0, stream>>>(Wv, wvt, ND, NO);
  // 2) projections (M=16384)
  gemm_bias_kernel<<<dim3(128, 8), 256, 0, stream>>>(xb, wqt, bq, Qb, NB * NS, ND, ND);
  gemm_bias_kernel<<<dim3(128, 8), 256, 0, stream>>>(xb, wkt, bk, Kb, NB * NS, ND, ND);
  gemm_bias_kernel<<<dim3(128, 4), 256, 0, stream>>>(xb, wvt, bv, Vb, NB * NS, NO, ND);
  // 3) V transpose -> [B][O][S]
  transpose_v_kernel<<<dim3(16, 64, 8), 256, 0, stream>>>(Vb, Vtb);
  // 4) flash attention, split-kv (2 blocks per (b,qi)) + combine
  flash_split_kernel<<<512, 256, 0, stream>>>(Qb, Kb, Vtb, opart, mlbuf);
  combine_kernel<<<256, 256, 0, stream>>>(opart, mlbuf, out);
}

// Round 7
// 487.808 us; speedup vs baseline: 1.2291x; 1.2291x over previous
//
#include <hip/hip_runtime.h>
#include <hip/hip_bf16.h>
#include <stdint.h>
#include <cmath>

typedef __bf16 bf16x8 __attribute__((ext_vector_type(8)));
typedef float f32x4 __attribute__((ext_vector_type(4)));

#define NB 8
#define NS 2048
#define ND 1024
#define NO 512

__device__ __forceinline__ unsigned short f2bf(float f) {
  union { float f; uint32_t u; } c;
  c.f = f;
  uint32_t u = c.u;
  uint32_t r = (u + 0x7fffu + ((u >> 16) & 1u)) >> 16;
  return (unsigned short)r;
}

__device__ __forceinline__ void glds16(const void* g, void* l) {
  __builtin_amdgcn_global_load_lds(
      (const __attribute__((address_space(1))) unsigned int*)g,
      (__attribute__((address_space(3))) unsigned int*)l, 16, 0, 0);
}

// ---------------- cast x (fp32 -> bf16), 8 elems/thread ----------------
__global__ void cast_x_kernel(const float* __restrict__ in,
                              unsigned short* __restrict__ out, int n8) {
  int i = blockIdx.x * blockDim.x + threadIdx.x;
  if (i >= n8) return;
  const float4* p = reinterpret_cast<const float4*>(in) + 2 * (size_t)i;
  float4 a = p[0], b = p[1];
  union { unsigned short us[8]; int4 v; } r;
  r.us[0] = f2bf(a.x); r.us[1] = f2bf(a.y); r.us[2] = f2bf(a.z); r.us[3] = f2bf(a.w);
  r.us[4] = f2bf(b.x); r.us[5] = f2bf(b.y); r.us[6] = f2bf(b.z); r.us[7] = f2bf(b.w);
  reinterpret_cast<int4*>(out)[i] = r.v;
}

// ------------- transpose+cast weights: in[R][C] f32 -> out[C][R] bf16 -------------
__global__ void transpose_cast_kernel(const float* __restrict__ in,
                                      unsigned short* __restrict__ out,
                                      int R, int C) {
  __shared__ unsigned short t[32][33];
  int bx = blockIdx.x;  // C/32
  int by = blockIdx.y;  // R/32
  int x = threadIdx.x & 31, y = threadIdx.x >> 5;  // y: 0..7
#pragma unroll
  for (int j = 0; j < 4; j++) {
    int r = by * 32 + y + j * 8;
    int c = bx * 32 + x;
    t[y + j * 8][x] = f2bf(in[(size_t)r * C + c]);
  }
  __syncthreads();
#pragma unroll
  for (int j = 0; j < 4; j++) {
    int c = bx * 32 + y + j * 8;
    int r = by * 32 + x;
    out[(size_t)c * R + r] = t[x][y + j * 8];
  }
}

// ------------- transpose V: [B][S][O] bf16 -> [B][O][S] bf16 -------------
__global__ void transpose_v_kernel(const unsigned short* __restrict__ in,
                                   unsigned short* __restrict__ out) {
  __shared__ unsigned short t[32][33];
  int b = blockIdx.z;
  int bo = blockIdx.x;  // O/32
  int bs = blockIdx.y;  // S/32
  const unsigned short* ib = in + (size_t)b * NS * NO;
  unsigned short* ob = out + (size_t)b * NO * NS;
  int x = threadIdx.x & 31, y = threadIdx.x >> 5;
#pragma unroll
  for (int j = 0; j < 4; j++)
    t[y + j * 8][x] = ib[(size_t)(bs * 32 + y + j * 8) * NO + bo * 32 + x];
  __syncthreads();
#pragma unroll
  for (int j = 0; j < 4; j++)
    ob[(size_t)(bo * 32 + y + j * 8) * NS + bs * 32 + x] = t[x][y + j * 8];
}

// ------------- GEMM: C[M][N] = A[M][K] @ Bt[N][K]^T + bias, bf16 in/out -------------
// T3 minimum-2-phase: double-buffered LDS, stage(t+1) issued before compute(t),
// one __syncthreads per K-step (drains vmcnt for the prefetch).
__global__ __launch_bounds__(256, 2) void gemm_bias_kernel(
    const unsigned short* __restrict__ A, const unsigned short* __restrict__ Bt,
    const float* __restrict__ bias, unsigned short* __restrict__ C,
    int M, int N, int K) {
  __shared__ unsigned short lA[2][128 * 32];
  __shared__ unsigned short lB[2][128 * 32];
  const int tid = threadIdx.x;
  const int w = tid >> 6, l = tid & 63;
  const int m0 = blockIdx.x * 128, n0 = blockIdx.y * 128;
  const int wr = w >> 1, wc = w & 1;
  const int lr16 = l & 15, lg = l >> 4;
  f32x4 acc[4][4];
#pragma unroll
  for (int i = 0; i < 4; i++)
#pragma unroll
    for (int j = 0; j < 4; j++) acc[i][j] = (f32x4){0.f, 0.f, 0.f, 0.f};
  const int srow = w * 32 + (l >> 2);
  const int sk = (l & 3) * 8;
  auto stage = [&](int buf, int k0) {
#pragma unroll
    for (int j = 0; j < 2; j++) {
      glds16(&A[(size_t)(m0 + srow + j * 16) * K + k0 + sk], &lA[buf][w * 1024 + j * 512]);
      glds16(&Bt[(size_t)(n0 + srow + j * 16) * K + k0 + sk], &lB[buf][w * 1024 + j * 512]);
    }
  };
  const int nt = K >> 5;
  stage(0, 0);
  __syncthreads();
  int cur = 0;
  for (int t = 0; t < nt; ++t) {
    if (t + 1 < nt) stage(cur ^ 1, (t + 1) * 32);
    bf16x8 af[4], bfr[4];
#pragma unroll
    for (int mi = 0; mi < 4; mi++)
      af[mi] = *reinterpret_cast<const bf16x8*>(&lA[cur][(wr * 64 + mi * 16 + lr16) * 32 + lg * 8]);
#pragma unroll
    for (int ni = 0; ni < 4; ni++)
      bfr[ni] = *reinterpret_cast<const bf16x8*>(&lB[cur][(wc * 64 + ni * 16 + lr16) * 32 + lg * 8]);
#pragma unroll
    for (int mi = 0; mi < 4; mi++)
#pragma unroll
      for (int ni = 0; ni < 4; ni++)
        acc[mi][ni] = __builtin_amdgcn_mfma_f32_16x16x32_bf16(af[mi], bfr[ni], acc[mi][ni], 0, 0, 0);
    __syncthreads();  // drains prefetch vmcnt + protects cur-buffer reuse
    cur ^= 1;
  }
#pragma unroll
  for (int ni = 0; ni < 4; ni++) {
    int col = n0 + wc * 64 + ni * 16 + lr16;
    float bv = bias[col];
#pragma unroll
    for (int mi = 0; mi < 4; mi++) {
#pragma unroll
      for (int i = 0; i < 4; i++) {
        int row = m0 + wr * 64 + mi * 16 + lg * 4 + i;
        C[(size_t)row * N + col] = f2bf(acc[mi][ni][i] + bv);
      }
    }
  }
}

// ------------- Flash attention SPLIT-KV: each block does k-tiles [lo,hi) of one (b,qi) -------------
// launch_bounds(256,1): state needs ~360 unified regs/wave (qreg 128 + acc_o 128 + temps);
// capping for 2 blocks/CU spills to scratch (round-4: FETCH 41->301MB, dur +40%). Occupancy
// comes from split-KV + LPT ordering instead (per-CU makespan ~16.5 k-tiles vs 32).
// 4 LDS buffers, vmcnt(8): two 16KB units in flight across barriers.
__global__ __launch_bounds__(256, 1) void flash_split_kernel(
    const unsigned short* __restrict__ Q, const unsigned short* __restrict__ K,
    const unsigned short* __restrict__ Vt, unsigned short* __restrict__ opart,
    float* __restrict__ ml) {
  __shared__ unsigned short ubuf[4 * 8192];  // 4 x 16KB pipeline buffers
  __shared__ unsigned short lP[64 * 64];     // 8KB, swizzled
  const int bid = blockIdx.x;
  const int b = bid & 7;
  const int t = bid >> 3;
  int qi, half;
  if (t < 32) { qi = 31 - (t >> 1); half = t & 1; }      // heavy halves first
  else        { int u2 = t - 32; qi = u2 >> 1; half = u2 & 1; }  // light halves last
  const int nkt = qi + 1;
  const int h = (qi + 2) >> 1;           // ceil(nkt/2)
  const int lo = half ? h : 0;
  const int hi = half ? nkt : h;
  const int total = 12 * (hi - lo);

  const int tid = threadIdx.x, w = tid >> 6, l = tid & 63;
  const unsigned short* Qb = Q + (size_t)b * NS * ND;
  const unsigned short* Kb = K + (size_t)b * NS * ND;
  const unsigned short* Vb = Vt + (size_t)b * NO * NS;
  const int q0 = qi * 64;
  const int lr16 = l & 15, lg = l >> 4;

  // ---- Q tile into registers: lane holds row (w*16+lr16), d-slice (c*32 + lg*8) ----
  bf16x8 qreg[32];
  {
    const unsigned short* qrow = &Qb[(size_t)(q0 + w * 16 + lr16) * ND + lg * 8];
#pragma unroll
    for (int c = 0; c < 32; c++)
      qreg[c] = *reinterpret_cast<const bf16x8*>(qrow + c * 32);
  }

  f32x4 acc_o[32];
#pragma unroll
  for (int f = 0; f < 32; f++) acc_o[f] = (f32x4){0.f, 0.f, 0.f, 0.f};
  float m_s[4], l_s[4];
#pragma unroll
  for (int i = 0; i < 4; i++) { m_s[i] = -INFINITY; l_s[i] = 0.f; }
  const float sc = 0.03125f * 1.4426950408889634f;  // 1/sqrt(1024) * log2(e)

  // stage relative unit g (k-tile lo + g/12) into buffer g%4
  auto stage = [&](int g) {
    int ki = lo + g / 12, u = g - (g / 12) * 12;
    int k0 = ki * 64;
    unsigned short* dst = &ubuf[(g & 3) * 8192];
    if (u < 8) {  // K unit u: [64 kv][128 d], d-range u*128
#pragma unroll
      for (int j = 0; j < 4; j++) {
        int row = j * 16 + w * 4 + (l >> 4);
        int gl = (l & 15) ^ (row & 7);  // inverse-swizzled source granule
        glds16(&Kb[(size_t)(k0 + row) * ND + u * 128 + gl * 8],
               dst + j * 2048 + w * 512);
      }
    } else {  // V unit nc: [128 O][64 kv], O-range nc*128
      int nc = u - 8;
#pragma unroll
      for (int j = 0; j < 4; j++) {
        int row = j * 32 + w * 8 + (l >> 3);
        int gl = (l & 7) ^ (row & 7);
        glds16(&Vb[(size_t)(nc * 128 + row) * NS + k0 + gl * 8],
               dst + j * 2048 + w * 512);
      }
    }
  };

  if (total > 0) {
    stage(0);
    if (total > 1) stage(1);
    if (total > 2) stage(2);

    bf16x8 pa0 = {}, pa1 = {};
    for (int ki = lo; ki < hi; ++ki) {
      const int gbase = (ki - lo) * 12;
      f32x4 accs[4];
#pragma unroll
      for (int f = 0; f < 4; f++) accs[f] = (f32x4){0.f, 0.f, 0.f, 0.f};

#pragma unroll
      for (int u = 0; u < 12; ++u) {
        const int g = gbase + u;
        const int rem = total - g;  // units remaining including this one
        if (rem > 2)
          asm volatile("s_waitcnt vmcnt(8) lgkmcnt(0)\ns_barrier" ::: "memory");
        else if (rem > 1)
          asm volatile("s_waitcnt vmcnt(4) lgkmcnt(0)\ns_barrier" ::: "memory");
        else
          asm volatile("s_waitcnt vmcnt(0) lgkmcnt(0)\ns_barrier" ::: "memory");
        if (g + 3 < total) stage(g + 3);
        const unsigned short* bp = &ubuf[(g & 3) * 8192];

        if (u < 8) {
          // ---- QK^T unit: S += Q[d-slice] * K[d-slice]^T ----
#pragma unroll
          for (int ks = 0; ks < 4; ks++) {
            bf16x8 a = qreg[u * 4 + ks];
#pragma unroll
            for (int fn = 0; fn < 4; fn++) {
              int row = fn * 16 + lr16;
              int p = (ks * 4 + lg) ^ (row & 7);
              bf16x8 bb = *reinterpret_cast<const bf16x8*>(&bp[row * 128 + p * 8]);
              accs[fn] = __builtin_amdgcn_mfma_f32_16x16x32_bf16(a, bb, accs[fn], 0, 0, 0);
            }
          }
          if (u == 7) {
            // ---- online softmax (wave-parallel, in-register) ----
            const bool diag = (ki == qi);
            float alpha[4];
#pragma unroll
            for (int i = 0; i < 4; i++) {
              float v0 = accs[0][i] * sc, v1 = accs[1][i] * sc;
              float v2 = accs[2][i] * sc, v3 = accs[3][i] * sc;
              if (diag) {
                int qr = w * 16 + lg * 4 + i;
                if (lr16 > qr) v0 = -INFINITY;
                if (16 + lr16 > qr) v1 = -INFINITY;
                if (32 + lr16 > qr) v2 = -INFINITY;
                if (48 + lr16 > qr) v3 = -INFINITY;
              }
              float pm = fmaxf(fmaxf(v0, v1), fmaxf(v2, v3));
              pm = fmaxf(pm, __shfl_xor(pm, 1));
              pm = fmaxf(pm, __shfl_xor(pm, 2));
              pm = fmaxf(pm, __shfl_xor(pm, 4));
              pm = fmaxf(pm, __shfl_xor(pm, 8));
              float mn = fmaxf(m_s[i], pm);
              float al = exp2f(m_s[i] - mn);
              float p0 = exp2f(v0 - mn), p1 = exp2f(v1 - mn);
              float p2 = exp2f(v2 - mn), p3 = exp2f(v3 - mn);
              float rs = (p0 + p1) + (p2 + p3);
              rs += __shfl_xor(rs, 1);
              rs += __shfl_xor(rs, 2);
              rs += __shfl_xor(rs, 4);
              rs += __shfl_xor(rs, 8);
              l_s[i] = l_s[i] * al + rs;
              m_s[i] = mn;
              alpha[i] = al;
              accs[0][i] = p0; accs[1][i] = p1; accs[2][i] = p2; accs[3][i] = p3;
            }
#pragma unroll
            for (int f = 0; f < 32; f++)
#pragma unroll
              for (int i = 0; i < 4; i++) acc_o[f][i] *= alpha[i];
            // ---- P -> LDS (bf16, swizzled) ----
#pragma unroll
            for (int fn = 0; fn < 4; fn++)
#pragma unroll
              for (int i = 0; i < 4; i++) {
                int pr = w * 16 + lg * 4 + i;
                int pg = (fn * 2 + (lr16 >> 3)) ^ (pr & 7);
                lP[pr * 64 + pg * 8 + (lr16 & 7)] = f2bf(accs[fn][i]);
              }
          }
        } else {
          // ---- PV unit nc: O += P * V ----
          const int nc = u - 8;
          if (u == 8) {
            int prow = w * 16 + lr16;
            pa0 = *reinterpret_cast<const bf16x8*>(&lP[prow * 64 + ((0 + lg) ^ (prow & 7)) * 8]);
            pa1 = *reinterpret_cast<const bf16x8*>(&lP[prow * 64 + ((4 + lg) ^ (prow & 7)) * 8]);
          }
#pragma unroll
          for (int fc = 0; fc < 8; fc++) {
            int row = fc * 16 + lr16;
            int p0i = (0 + lg) ^ (row & 7);
            int p1i = (4 + lg) ^ (row & 7);
            bf16x8 b0 = *reinterpret_cast<const bf16x8*>(&bp[row * 64 + p0i * 8]);
            bf16x8 b1 = *reinterpret_cast<const bf16x8*>(&bp[row * 64 + p1i * 8]);
            int f = nc * 8 + fc;
            acc_o[f] = __builtin_amdgcn_mfma_f32_16x16x32_bf16(pa0, b0, acc_o[f], 0, 0, 0);
            acc_o[f] = __builtin_amdgcn_mfma_f32_16x16x32_bf16(pa1, b1, acc_o[f], 0, 0, 0);
          }
        }
      }
    }
  }

  // ---- epilogue: write unnormalized partial O (bf16) + m,l (f32) ----
  const int slot = (qi * 2 + half) * 8 + b;
  unsigned short* op = opart + (size_t)slot * 64 * 512;
#pragma unroll
  for (int nc = 0; nc < 4; nc++)
#pragma unroll
    for (int fc = 0; fc < 8; fc++)
#pragma unroll
      for (int i = 0; i < 4; i++) {
        int row = w * 16 + lg * 4 + i;
        int col = nc * 128 + fc * 16 + lr16;
        op[(size_t)row * 512 + col] = f2bf(acc_o[nc * 8 + fc][i]);
      }
  float* mlp = ml + slot * 128;
  if (lr16 == 0) {
#pragma unroll
    for (int i = 0; i < 4; i++) {
      int row = w * 16 + lg * 4 + i;
      mlp[row] = m_s[i];
      mlp[64 + row] = l_s[i];
    }
  }
}

// ------------- combine: merge two partials -> final fp32 out -------------
__global__ __launch_bounds__(256) void combine_kernel(
    const unsigned short* __restrict__ opart, const float* __restrict__ ml,
    float* __restrict__ Out) {
  const int bid = blockIdx.x;
  const int b = bid & 7, qi = bid >> 3;
  const int tid = threadIdx.x;
  const int c8 = (tid & 63) * 8;
  const int rbase = (tid >> 6) * 16;
  const int sA = (qi * 2 + 0) * 8 + b;
  const int sB = sA + 8;
  const unsigned short* OA = opart + (size_t)sA * 32768;
  const unsigned short* OB = opart + (size_t)sB * 32768;
  const float* mlA = ml + sA * 128;
  const float* mlB = ml + sB * 128;
  float* ob = Out + ((size_t)b * NS + qi * 64) * NO;
#pragma unroll
  for (int rr = 0; rr < 16; rr++) {
    int r = rbase + rr;
    float mA = mlA[r], lA = mlA[64 + r];
    float mB = mlB[r], lB = mlB[64 + r];
    float m = fmaxf(mA, mB);
    float eA = exp2f(mA - m);
    float eB = (mB == -INFINITY) ? 0.f : exp2f(mB - m);
    float inv = 1.0f / (eA * lA + eB * lB);
    bf16x8 a = *reinterpret_cast<const bf16x8*>(&OA[(size_t)r * 512 + c8]);
    bf16x8 bb = *reinterpret_cast<const bf16x8*>(&OB[(size_t)r * 512 + c8]);
    float4 o0, o1;
    o0.x = ((float)a[0] * eA + (float)bb[0] * eB) * inv;
    o0.y = ((float)a[1] * eA + (float)bb[1] * eB) * inv;
    o0.z = ((float)a[2] * eA + (float)bb[2] * eB) * inv;
    o0.w = ((float)a[3] * eA + (float)bb[3] * eB) * inv;
    o1.x = ((float)a[4] * eA + (float)bb[4] * eB) * inv;
    o1.y = ((float)a[5] * eA + (float)bb[5] * eB) * inv;
    o1.z = ((float)a[6] * eA + (float)bb[6] * eB) * inv;
    o1.w = ((float)a[7] * eA + (float)bb[7] * eB) * inv;
    float4* dst = reinterpret_cast<float4*>(&ob[(size_t)r * 512 + c8]);
    dst[0] = o0;
    dst[1] = o1;
  }
}

extern "C" void kernel_launch(void* const* d_in, const int* in_sizes, int n_in,
                              void* d_out, int out_size, void* d_ws, size_t ws_size,
                              hipStream_t stream) {
  const float* x = (const float*)d_in[0];
  const float* Wq = (const float*)d_in[1];
  const float* bq = (const float*)d_in[2];
  const float* Wk = (const float*)d_in[3];
  const float* bk = (const float*)d_in[4];
  const float* Wv = (const float*)d_in[5];
  const float* bv = (const float*)d_in[6];
  float* out = (float*)d_out;
  char* ws = (char*)d_ws;

  // workspace layout (bytes)
  unsigned short* xb  = (unsigned short*)(ws + 0);          // 33,554,432 (dead after GEMMs)
  unsigned short* wqt = (unsigned short*)(ws + 33554432);   //  2,097,152
  unsigned short* wkt = (unsigned short*)(ws + 35651584);   //  2,097,152
  unsigned short* wvt = (unsigned short*)(ws + 37748736);   //  1,048,576
  unsigned short* Qb  = (unsigned short*)(ws + 38797312);   // 33,554,432
  unsigned short* Kb  = (unsigned short*)(ws + 72351744);   // 33,554,432
  unsigned short* Vb  = (unsigned short*)(ws + 105906176);  // 16,777,216 (dead after transpose_v)
  unsigned short* Vtb = (unsigned short*)(ws + 122683392);  // 16,777,216  (end ~133MB)
  // reuse dead regions for split-kv partials:
  unsigned short* opart = xb;                               // 512*64*512*2 = 33,554,432 (fits xb exactly)
  float* mlbuf = (float*)(ws + 105906176);                  // 512*128*4 = 262,144 (in Vb region)

  // 1) casts
  cast_x_kernel<<<8192, 256, 0, stream>>>(x, xb, (NB * NS * ND) / 8);
  transpose_cast_kernel<<<dim3(32, 32), 256, 0, stream>>>(Wq, wqt, ND, ND);
  transpose_cast_kernel<<<dim3(32, 32), 256, 0, stream>>>(Wk, wkt, ND, ND);
  transpose_cast_kernel<<<dim3(16, 32), 256, 0, stream>>>(Wv, wvt, ND, NO);
  // 2) projections (M=16384)
  gemm_bias_kernel<<<dim3(128, 8), 256, 0, stream>>>(xb, wqt, bq, Qb, NB * NS, ND, ND);
  gemm_bias_kernel<<<dim3(128, 8), 256, 0, stream>>>(xb, wkt, bk, Kb, NB * NS, ND, ND);
  gemm_bias_kernel<<<dim3(128, 4), 256, 0, stream>>>(xb, wvt, bv, Vb, NB * NS, NO, ND);
  // 3) V transpose -> [B][O][S]
  transpose_v_kernel<<<dim3(16, 64, 8), 256, 0, stream>>>(Vb, Vtb);
  // 4) flash attention, split-kv (2 blocks per (b,qi)) + combine
  flash_split_kernel<<<512, 256, 0, stream>>>(Qb, Kb, Vtb, opart, mlbuf);
  combine_kernel<<<256, 256, 0, stream>>>(opart, mlbuf, out);
}